// Round 9
// baseline (234.963 us; speedup 1.0000x reference)
//
#include <hip/hip_runtime.h>
#include <hip/hip_bf16.h>
#include <stdint.h>

// LSTM cell as one fused bf16 MFMA GEMM (R7 schedule + fused A-conversion):
//   gates(8192 x 4096) = A(8192 x 2048) @ Bp(4096 x 2048)^T, fused LSTM epilogue.
// A = [x | h_prev] converted f32->bf16 ON THE FLY in the GEMM's A-staging path
// (pack_A kernel deleted: saves a 96MB HBM round-trip). Bp rows gate-interleaved
// per 16 hidden units: packed row r=(h/16)*64+g*16+(h%16) -> wave's 4 N-frags
// = 4 gates of same h -> LSTM epilogue fully in-register.
//
// GEMM = round-7 structure (best measured: 153.6us wall, ~1083 TF warm):
// 256x256 tile, BK=64, 8 waves (2Mx4N), MFMA-first 4 phases/K-tile, one
// barrier per phase, operands read one phase ahead (ping-pong regs), B in LDS
// dbuf staged via global_load_lds w/ counted vmcnt, A reg-staged (now f32->cvt).

#define B_DIM 8192
#define I_DIM 1024
#define H_DIM 1024
#define K_DIM 2048   // I + H
#define N_DIM 4096   // 4 gates * H
#define NKT   32     // K_DIM / 64

typedef short bf16x8 __attribute__((ext_vector_type(8)));
typedef float f32x4 __attribute__((ext_vector_type(4)));

__device__ __forceinline__ unsigned short f2bf(float f) {
  unsigned int u = __float_as_uint(f);
  u += 0x7FFFu + ((u >> 16) & 1u);   // RNE
  return (unsigned short)(u >> 16);
}

__device__ __forceinline__ short f2bf16s(float f) {
  __hip_bfloat16 t = __float2bfloat16(f);   // RNE; compiler pairs into v_cvt_pk_bf16_f32
  return *reinterpret_cast<short*>(&t);
}

__device__ __forceinline__ bf16x8 cvt8(float4 a, float4 b) {
  bf16x8 o;
  o[0] = f2bf16s(a.x); o[1] = f2bf16s(a.y); o[2] = f2bf16s(a.z); o[3] = f2bf16s(a.w);
  o[4] = f2bf16s(b.x); o[5] = f2bf16s(b.y); o[6] = f2bf16s(b.z); o[7] = f2bf16s(b.w);
  return o;
}

// ---- pack B: 8 weight mats -> bf16 (N_DIM, K_DIM), gate-interleaved rows ----
__global__ void pack_B_kernel(const float* __restrict__ Wxi, const float* __restrict__ Whi,
                              const float* __restrict__ Wxf, const float* __restrict__ Whf,
                              const float* __restrict__ Wxc, const float* __restrict__ Whc,
                              const float* __restrict__ Wxo, const float* __restrict__ Who,
                              unsigned short* __restrict__ outB) {
  const int total = N_DIM * K_DIM / 8;
  for (int idx = blockIdx.x * blockDim.x + threadIdx.x; idx < total;
       idx += gridDim.x * blockDim.x) {
    int r = idx >> 8;
    int k = (idx & 255) * 8;
    int g = (r >> 4) & 3;
    int h = ((r >> 6) << 4) | (r & 15);
    const float* base;
    if (k < I_DIM) {
      base = (g == 0) ? Wxi : (g == 1) ? Wxf : (g == 2) ? Wxc : Wxo;
      base += (size_t)h * I_DIM + k;
    } else {
      base = (g == 0) ? Whi : (g == 1) ? Whf : (g == 2) ? Whc : Who;
      base += (size_t)h * H_DIM + (k - I_DIM);
    }
    const float4* s4 = (const float4*)base;
    float4 v0 = s4[0], v1 = s4[1];
    bf16x8 o;
    o[0] = f2bf(v0.x); o[1] = f2bf(v0.y); o[2] = f2bf(v0.z); o[3] = f2bf(v0.w);
    o[4] = f2bf(v1.x); o[5] = f2bf(v1.y); o[6] = f2bf(v1.z); o[7] = f2bf(v1.w);
    *(bf16x8*)(outB + (size_t)idx * 8) = o;
  }
}

// ---- GEMM 256x256 tile, BK=64, 8 waves (2Mx4N) ----
// LDS map (bytes): sA[buf] = buf*32768 (0..65536), sB[buf][half] = 65536 + ...

#define STAGE_B(gptr, slotoff, ktile) do {                                        \
    int _ktc = (ktile) < NKT ? (ktile) : (NKT - 1);                               \
    const unsigned short* _g = (gptr) + (size_t)_ktc * 64;                        \
    __builtin_amdgcn_global_load_lds(                                             \
        (const __attribute__((address_space(1))) void*)_g,                        \
        (__attribute__((address_space(3))) void*)(lds + (slotoff) + wid * 1024),  \
        16, 0, 0);                                                                \
    __builtin_amdgcn_global_load_lds(                                             \
        (const __attribute__((address_space(1))) void*)(_g + (size_t)64 * K_DIM), \
        (__attribute__((address_space(3))) void*)(lds + (slotoff) + 8192 + wid * 1024), \
        16, 0, 0);                                                                \
  } while (0)

// quadrant (MH, k-half): 4 A ds_reads + 16 independent MFMA
#define QUAD(MH, KOFF, BR) do {                                               \
    bf16x8 aq[4];                                                             \
    _Pragma("unroll") for (int mf = 0; mf < 4; ++mf)                          \
      aq[mf] = *(const bf16x8*)(ldsAr + _bo + (MH)*8192 + mf * 2048 + (KOFF));\
    __builtin_amdgcn_s_setprio(1);                                            \
    _Pragma("unroll") for (int mf = 0; mf < 4; ++mf)                          \
    _Pragma("unroll") for (int nn = 0; nn < 4; ++nn)                          \
      acc[(MH)*4 + mf][nn] = __builtin_amdgcn_mfma_f32_16x16x32_bf16(         \
          aq[mf], BR[nn], acc[(MH)*4 + mf][nn], 0, 0, 0);                     \
    __builtin_amdgcn_s_setprio(0);                                            \
  } while (0)

// A(T+1) f32 source pointer for this thread (kt clamped; branch is uniform)
#define A_SRC(KTC) ((((KTC) < 16) ? (xg + (size_t)arow * I_DIM + (KTC) * 64)      \
                                  : (hg + (size_t)arow * H_DIM + ((KTC) - 16) * 64)) + acol)

#define KTILE(BUF, KT, BC0, BN0) do {                                         \
    const int _bo  = (BUF) * 32768;                                           \
    const int _bo1 = ((BUF) ^ 1) * 32768;                                     \
    int _kt1 = (KT) + 1 < NKT ? (KT) + 1 : NKT - 1;                           \
    const float4* _as = (const float4*)A_SRC(_kt1);                           \
    float4 f0 = _as[0], f1 = _as[1], f2 = _as[2], f3 = _as[3];                \
    _Pragma("unroll") for (int nn = 0; nn < 4; ++nn)                          \
      Bk1[nn] = *(const bf16x8*)(gBfr + (size_t)(KT) * 4096 + 2048 + nn*512); \
    _Pragma("unroll") for (int nn = 0; nn < 4; ++nn)                          \
      BN0[nn] = *(const bf16x8*)(gBfr + (size_t)_kt1 * 4096 + nn * 512);      \
    QUAD(0, rd0, BC0);                                                        \
    QUAD(1, rd0, BC0);                                                        \
    *(bf16x8*)(ldsAw + _bo1 + woff0) = cvt8(f0, f1);                          \
    *(bf16x8*)(ldsAw + _bo1 + woff1) = cvt8(f2, f3);                          \
    float4 f4 = _as[4], f5 = _as[5], f6 = _as[6], f7 = _as[7];                \
    QUAD(0, rd1, Bk1);                                                        \
    QUAD(1, rd1, Bk1);                                                        \
    *(bf16x8*)(ldsAw + _bo1 + woff2) = cvt8(f4, f5);                          \
    *(bf16x8*)(ldsAw + _bo1 + woff3) = cvt8(f6, f7);                          \
    __syncthreads();                                                          \
  } while (0)

__launch_bounds__(512, 2)
__global__ void lstm_gemm_kernel(const float* __restrict__ xg,
                                 const float* __restrict__ hg,
                                 const unsigned short* __restrict__ Bp,
                                 const float* __restrict__ c_prev,
                                 const float* __restrict__ bxi, const float* __restrict__ bhi,
                                 const float* __restrict__ bxf, const float* __restrict__ bhf,
                                 const float* __restrict__ bxc, const float* __restrict__ bhc,
                                 const float* __restrict__ bxo, const float* __restrict__ bho,
                                 float* __restrict__ out) {
  __shared__ __align__(16) char lds[131072];  // A dbuf 64KB + B dbuf 64KB

  // XCD-aware bijective swizzle (512 % 8 == 0)
  const int nwg = gridDim.x;
  int bid = blockIdx.x;
  int q = nwg >> 3;
  int wg = (bid & 7) * q + (bid >> 3);
  int bm = wg >> 4;          // 32 M-tiles
  int bn = wg & 15;          // 16 N-tiles

  int tid = threadIdx.x;
  int lane = tid & 63;
  int wid = tid >> 6;        // 8 waves
  int wm = wid >> 2;         // 2 M-wave rows (128 rows each)
  int wn = wid & 3;          // 4 N-wave cols (64 cols each)

  // ---- A reg-staging: thread t owns row t>>1, 32-float half (t&1) ----
  int arow = bm * 256 + (tid >> 1);
  int acol = (tid & 1) * 32;
  char* ldsAw = lds + (tid >> 1) * 128;
  int wr7 = (tid >> 1) & 7;
  int woff0 = ((((tid & 1) * 4 + 0) ^ wr7) << 4);
  int woff1 = ((((tid & 1) * 4 + 1) ^ wr7) << 4);
  int woff2 = ((((tid & 1) * 4 + 2) ^ wr7) << 4);
  int woff3 = ((((tid & 1) * 4 + 3) ^ wr7) << 4);

  // ---- B staging (global_load_lds, pre-swizzled source; rule #21) ----
  int srow = lane >> 3;
  int schunk = (lane & 7) ^ srow;
  const unsigned short* gB0p = Bp + (size_t)(bn * 256 + wid * 8 + srow) * K_DIM + schunk * 8;
  const unsigned short* gB1p = gB0p + (size_t)128 * K_DIM;

  // ---- B fragment reads from LDS ----
  int c15 = lane & 15;
  int kl = lane >> 4;
  const char* ldsAr = lds + wm * 16384 + c15 * 128;
  const char* ldsBr = lds + 65536 + (wn >> 1) * 16384 + ((wn & 1) * 64 + c15) * 128;
  int rd0 = ((kl) ^ (lane & 7)) << 4;
  int rd1 = ((4 | kl) ^ (lane & 7)) << 4;
  (void)ldsBr;

  f32x4 acc[8][4];
  f32x4 zero = {0.f, 0.f, 0.f, 0.f};
#pragma unroll
  for (int m = 0; m < 8; ++m)
#pragma unroll
    for (int n = 0; n < 4; ++n) acc[m][n] = zero;

  // ---- B fragment stream kept as in R7: read from LDS? NO — R7 kept B in LDS
  // with ds reads inside QUAD's BR regs loaded one phase ahead. Reproduce R7
  // exactly: B frags are ds-read from LDS B buffers (BHa/BHb pattern folded
  // into Bk0A/Bk0B/Bk1 register groups below).
  bf16x8 Bk0A[4], Bk0B[4], Bk1[4];

  // B LDS read base (same formula as R7's ldsBr)
  const char* ldsBrd = lds + 65536 + (wn >> 1) * 16384 + ((wn & 1) * 64 + c15) * 128;

  // redefine the in-KTILE B reads to come from LDS (R7 semantics):
  // Bk1 = buf[BUF] kk1 ; BN0 = buf[BUF^1] kk0 (next tile, staged this tile).
  // Staging: B(T+2) into buf[BUF] after its last read (kk1 read at tile top).
#undef KTILE
#define KTILE(BUF, KT, BC0, BN0) do {                                         \
    const int _bo  = (BUF) * 32768;                                           \
    const int _bo1 = ((BUF) ^ 1) * 32768;                                     \
    int _kt1 = (KT) + 1 < NKT ? (KT) + 1 : NKT - 1;                           \
    const float4* _as = (const float4*)A_SRC(_kt1);                           \
    float4 f0 = _as[0], f1 = _as[1], f2 = _as[2], f3 = _as[3];                \
    _Pragma("unroll") for (int nn = 0; nn < 4; ++nn)                          \
      Bk1[nn] = *(const bf16x8*)(ldsBrd + _bo + nn * 2048 + rd1);             \
    _Pragma("unroll") for (int nn = 0; nn < 4; ++nn)                          \
      BN0[nn] = *(const bf16x8*)(ldsBrd + _bo1 + nn * 2048 + rd0);            \
    QUAD(0, rd0, BC0);                                                        \
    QUAD(1, rd0, BC0);                                                        \
    *(bf16x8*)(ldsAw + _bo1 + woff0) = cvt8(f0, f1);                          \
    *(bf16x8*)(ldsAw + _bo1 + woff1) = cvt8(f2, f3);                          \
    STAGE_B(gB0p, 65536 + _bo, (KT) + 2);                                     \
    float4 f4 = _as[4], f5 = _as[5], f6 = _as[6], f7 = _as[7];                \
    QUAD(0, rd1, Bk1);                                                        \
    QUAD(1, rd1, Bk1);                                                        \
    *(bf16x8*)(ldsAw + _bo1 + woff2) = cvt8(f4, f5);                          \
    *(bf16x8*)(ldsAw + _bo1 + woff3) = cvt8(f6, f7);                          \
    STAGE_B(gB1p, 65536 + _bo + 16384, (KT) + 2);                             \
    asm volatile("s_waitcnt vmcnt(4)" ::: "memory");                          \
    __syncthreads();                                                          \
  } while (0)

  // ---- prologue: stage B(0)->buf0, B(1)->buf1 (8 gload_lds); A(0)->buf0
  // via cvt path; then pre-read first-phase operands. ----
  STAGE_B(gB0p, 65536, 0);
  STAGE_B(gB1p, 65536 + 16384, 0);
  STAGE_B(gB0p, 65536 + 32768, 1);
  STAGE_B(gB1p, 65536 + 32768 + 16384, 1);
  {
    const float4* _as = (const float4*)A_SRC(0);
    float4 f0 = _as[0], f1 = _as[1], f2 = _as[2], f3 = _as[3];
    float4 f4 = _as[4], f5 = _as[5], f6 = _as[6], f7 = _as[7];
    *(bf16x8*)(ldsAw + woff0) = cvt8(f0, f1);
    *(bf16x8*)(ldsAw + woff1) = cvt8(f2, f3);
    *(bf16x8*)(ldsAw + woff2) = cvt8(f4, f5);
    *(bf16x8*)(ldsAw + woff3) = cvt8(f6, f7);
  }
  asm volatile("s_waitcnt vmcnt(4)" ::: "memory");   // B(0) landed; B(1) in flight
  __syncthreads();
#pragma unroll
  for (int nn = 0; nn < 4; ++nn)
    Bk0A[nn] = *(const bf16x8*)(ldsBrd + nn * 2048 + rd0);   // tile0 kk0

#pragma unroll 1
  for (int kt = 0; kt < NKT; kt += 2) {
    KTILE(0, kt, Bk0A, Bk0B);
    KTILE(1, kt + 1, Bk0B, Bk0A);
  }

  // ---- fused LSTM epilogue: lane owns hidden unit h; acc[mi][g][j] = gate g ----
  int h = (bn * 4 + wn) * 16 + c15;
  float bi = bxi[h] + bhi[h];
  float bf_ = bxf[h] + bhf[h];
  float bc = bxc[h] + bhc[h];
  float bo = bxo[h] + bho[h];
  int row0 = bm * 256 + wm * 128 + kl * 4;
#pragma unroll
  for (int mi = 0; mi < 8; ++mi) {
#pragma unroll
    for (int j = 0; j < 4; ++j) {
      int r = row0 + mi * 16 + j;
      size_t off = (size_t)r * H_DIM + h;
      float zi = acc[mi][0][j] + bi;
      float zf = acc[mi][1][j] + bf_;
      float zc = acc[mi][2][j] + bc;
      float zo = acc[mi][3][j] + bo;
      float ig = 1.f / (1.f + __expf(-zi));
      float fg = 1.f / (1.f + __expf(-zf));
      float e2 = __expf(-2.f * zc);
      float gg = (1.f - e2) / (1.f + e2);       // tanh(zc)
      float og = 1.f / (1.f + __expf(-zo));
      float cp = c_prev[off];
      float cn = fg * cp + ig * gg;
      float e2c = __expf(-2.f * cn);
      float th = (1.f - e2c) / (1.f + e2c);     // tanh(cn)
      out[off] = og * th;                        // h_new
      out[(size_t)B_DIM * H_DIM + off] = cn;     // c_new
    }
  }
}

extern "C" void kernel_launch(void* const* d_in, const int* in_sizes, int n_in,
                              void* d_out, int out_size, void* d_ws, size_t ws_size,
                              hipStream_t stream) {
  const float* x      = (const float*)d_in[0];
  const float* h_prev = (const float*)d_in[1];
  const float* c_prev = (const float*)d_in[2];
  const float* Wxi = (const float*)d_in[3];
  const float* Whi = (const float*)d_in[4];
  const float* Wxf = (const float*)d_in[5];
  const float* Whf = (const float*)d_in[6];
  const float* Wxc = (const float*)d_in[7];
  const float* Whc = (const float*)d_in[8];
  const float* Wxo = (const float*)d_in[9];
  const float* Who = (const float*)d_in[10];
  const float* bxi = (const float*)d_in[11];
  const float* bhi = (const float*)d_in[12];
  const float* bxf = (const float*)d_in[13];
  const float* bhf = (const float*)d_in[14];
  const float* bxc = (const float*)d_in[15];
  const float* bhc = (const float*)d_in[16];
  const float* bxo = (const float*)d_in[17];
  const float* bho = (const float*)d_in[18];

  unsigned short* Bbf = (unsigned short*)d_ws;   // 16 MiB

  pack_B_kernel<<<1024, 256, 0, stream>>>(Wxi, Whi, Wxf, Whf, Wxc, Whc, Wxo, Who, Bbf);
  lstm_gemm_kernel<<<512, 512, 0, stream>>>(x, h_prev, Bbf, c_prev,
      bxi, bhi, bxf, bhf, bxc, bhc, bxo, bho, (float*)d_out);
}

// Round 10
// 152.678 us; speedup vs baseline: 1.5389x; 1.5389x over previous
//
#include <hip/hip_runtime.h>
#include <hip/hip_bf16.h>
#include <stdint.h>

// LSTM cell as one fused bf16 MFMA GEMM (R7 schedule, verified best: 153.6us):
//   gates(8192 x 4096) = A(8192 x 2048) @ Bp(4096 x 2048)^T, fused LSTM epilogue.
// A = [x | h_prev] bf16.  Bp rows gate-interleaved per 16 hidden units:
//   packed row r = (h/16)*64 + g*16 + (h%16) -> wave's 4 N-frags = 4 gates of same h.
//
// ROUND 10: GEMM is byte-identical to round 7 (best measured). Change: the two
// pack kernels are merged into ONE grid-stride kernel (one less launch gap;
// better tail). R9's fused-cvt attempt is reverted — its plain f32 loads
// interleaved with the global_load_lds queue forced vmcnt(0)-equivalent drains
// every K-tile (in-order vmcnt queue couples completion).

#define B_DIM 8192
#define I_DIM 1024
#define H_DIM 1024
#define K_DIM 2048   // I + H
#define N_DIM 4096   // 4 gates * H
#define NKT   32     // K_DIM / 64

typedef short bf16x8 __attribute__((ext_vector_type(8)));
typedef float f32x4 __attribute__((ext_vector_type(4)));

__device__ __forceinline__ unsigned short f2bf(float f) {
  unsigned int u = __float_as_uint(f);
  u += 0x7FFFu + ((u >> 16) & 1u);   // RNE
  return (unsigned short)(u >> 16);
}

// ---- merged pack: A = [x|h] -> bf16 row-major (B_DIM,K_DIM);
//      B = 8 weight mats -> bf16 (N_DIM,K_DIM), gate-interleaved rows ----
__global__ void pack_AB_kernel(const float* __restrict__ x, const float* __restrict__ h,
                               const float* __restrict__ Wxi, const float* __restrict__ Whi,
                               const float* __restrict__ Wxf, const float* __restrict__ Whf,
                               const float* __restrict__ Wxc, const float* __restrict__ Whc,
                               const float* __restrict__ Wxo, const float* __restrict__ Who,
                               unsigned short* __restrict__ outA,
                               unsigned short* __restrict__ outB) {
  const int totalA = B_DIM * K_DIM / 8;             // 2M 16B-units
  const int total  = totalA + N_DIM * K_DIM / 8;    // +1M
  for (int idx = blockIdx.x * blockDim.x + threadIdx.x; idx < total;
       idx += gridDim.x * blockDim.x) {
    const float* src;
    unsigned short* dst;
    if (idx < totalA) {
      int row = idx >> 8;              // K_DIM/8 = 256 units/row
      int col = (idx & 255) * 8;
      src = (col < I_DIM) ? (x + (size_t)row * I_DIM + col)
                          : (h + (size_t)row * H_DIM + (col - I_DIM));
      dst = outA + (size_t)idx * 8;
    } else {
      int u2 = idx - totalA;
      int r = u2 >> 8;
      int k = (u2 & 255) * 8;
      int g = (r >> 4) & 3;
      int hh = ((r >> 6) << 4) | (r & 15);
      src = (k < I_DIM)
          ? ((g == 0 ? Wxi : g == 1 ? Wxf : g == 2 ? Wxc : Wxo) + (size_t)hh * I_DIM + k)
          : ((g == 0 ? Whi : g == 1 ? Whf : g == 2 ? Whc : Who) + (size_t)hh * H_DIM + (k - I_DIM));
      dst = outB + (size_t)u2 * 8;
    }
    const float4* s4 = (const float4*)src;
    float4 v0 = s4[0], v1 = s4[1];
    bf16x8 o;
    o[0] = f2bf(v0.x); o[1] = f2bf(v0.y); o[2] = f2bf(v0.z); o[3] = f2bf(v0.w);
    o[4] = f2bf(v1.x); o[5] = f2bf(v1.y); o[6] = f2bf(v1.z); o[7] = f2bf(v1.w);
    *(bf16x8*)dst = o;
  }
}

// ---- GEMM 256x256 tile, BK=64, 8 waves (2Mx4N) — byte-identical to R7 ----
// LDS map (bytes): sA[buf][half] = buf*32768 + half*16384            (0..65536)
//                  sB[buf][half] = 65536 + buf*32768 + half*16384    (65536..131072)

#define STAGE(gptr, slotoff, ktile) do {                                          \
    int _ktc = (ktile) < NKT ? (ktile) : (NKT - 1);                               \
    const unsigned short* _g = (gptr) + (size_t)_ktc * 64;                        \
    __builtin_amdgcn_global_load_lds(                                             \
        (const __attribute__((address_space(1))) void*)_g,                        \
        (__attribute__((address_space(3))) void*)(lds + (slotoff) + wid * 1024),  \
        16, 0, 0);                                                                \
    __builtin_amdgcn_global_load_lds(                                             \
        (const __attribute__((address_space(1))) void*)(_g + (size_t)64 * K_DIM), \
        (__attribute__((address_space(3))) void*)(lds + (slotoff) + 8192 + wid * 1024), \
        16, 0, 0);                                                                \
  } while (0)

// phase (MH, kk): 16 independent MFMAs, acc rows MH*4..MH*4+3, one kk slice
#define MFMAP(MH, AR, BR)                                                         \
  _Pragma("unroll") for (int mf = 0; mf < 4; ++mf)                                \
  _Pragma("unroll") for (int nn = 0; nn < 4; ++nn)                                \
    acc[(MH)*4 + mf][nn] = __builtin_amdgcn_mfma_f32_16x16x32_bf16(               \
        AR[mf], BR[nn], acc[(MH)*4 + mf][nn], 0, 0, 0)

#define RD_AQ(DST, MH, KOFF, BO)                                                  \
  _Pragma("unroll") for (int mf = 0; mf < 4; ++mf)                                \
    DST[mf] = *(const bf16x8*)(ldsAr + (BO) + (MH)*8192 + mf * 2048 + (KOFF));

#define RD_BH(DST, KOFF, BO)                                                      \
  _Pragma("unroll") for (int nn = 0; nn < 4; ++nn)                                \
    DST[nn] = *(const bf16x8*)(ldsBr + (BO) + nn * 2048 + (KOFF));

#define KTILE(BUF, KT) do {                                                       \
    const int _bo = (BUF) * 32768;                                                \
    const int _bo1 = ((BUF) ^ 1) * 32768;                                         \
    /* p0 */                                                                      \
    __builtin_amdgcn_s_setprio(1);                                                \
    MFMAP(0, AQa, BHa);                                                           \
    __builtin_amdgcn_s_setprio(0);                                                \
    RD_AQ(AQb, 1, rd0, _bo);                                                      \
    __builtin_amdgcn_s_barrier();                                                 \
    /* p1 */                                                                      \
    __builtin_amdgcn_s_setprio(1);                                                \
    MFMAP(1, AQb, BHa);                                                           \
    __builtin_amdgcn_s_setprio(0);                                                \
    RD_BH(BHb, rd1, _bo);                                                         \
    RD_AQ(AQa, 0, rd1, _bo);                                                      \
    __builtin_amdgcn_s_barrier();                                                 \
    /* p2 */                                                                      \
    __builtin_amdgcn_s_setprio(1);                                                \
    MFMAP(0, AQa, BHb);                                                           \
    __builtin_amdgcn_s_setprio(0);                                                \
    RD_AQ(AQb, 1, rd1, _bo);                                                      \
    STAGE(gB0p, 65536 + _bo, (KT) + 2);                                           \
    STAGE(gB1p, 65536 + _bo + 16384, (KT) + 2);                                   \
    asm volatile("s_waitcnt vmcnt(4)" ::: "memory");                              \
    __builtin_amdgcn_s_barrier();                                                 \
    /* p3 */                                                                      \
    __builtin_amdgcn_s_setprio(1);                                                \
    MFMAP(1, AQb, BHb);                                                           \
    __builtin_amdgcn_s_setprio(0);                                                \
    RD_AQ(AQa, 0, rd0, _bo1);                                                     \
    RD_BH(BHa, rd0, _bo1);                                                        \
    STAGE(gA0p, _bo, (KT) + 2);                                                   \
    STAGE(gA1p, _bo + 16384, (KT) + 2);                                           \
    __builtin_amdgcn_s_barrier();                                                 \
  } while (0)

__launch_bounds__(512, 2)
__global__ void lstm_gemm_kernel(const unsigned short* __restrict__ A,
                                 const unsigned short* __restrict__ Bp,
                                 const float* __restrict__ c_prev,
                                 const float* __restrict__ bxi, const float* __restrict__ bhi,
                                 const float* __restrict__ bxf, const float* __restrict__ bhf,
                                 const float* __restrict__ bxc, const float* __restrict__ bhc,
                                 const float* __restrict__ bxo, const float* __restrict__ bho,
                                 float* __restrict__ out) {
  __shared__ __align__(16) char lds[131072];

  // XCD-aware bijective swizzle (512 % 8 == 0)
  const int nwg = gridDim.x;
  int bid = blockIdx.x;
  int q = nwg >> 3;
  int wg = (bid & 7) * q + (bid >> 3);
  int bm = wg >> 4;          // 32 M-tiles
  int bn = wg & 15;          // 16 N-tiles

  int tid = threadIdx.x;
  int lane = tid & 63;
  int wid = tid >> 6;        // 8 waves
  int wm = wid >> 2;         // 2 M-wave rows (128 rows each)
  int wn = wid & 3;          // 4 N-wave cols (64 cols each)

  // staging addresses: per half-tile, wave covers 8 rows x 128B; pre-swizzled
  // global source (rule #21): linear LDS dest, src chunk XOR row&7, same XOR on read.
  int srow = lane >> 3;                 // row within 8-row stripe
  int schunk = (lane & 7) ^ srow;       // swizzled 16B chunk
  const unsigned short* gA0p = A  + (size_t)(bm * 256 + wid * 8 + srow) * K_DIM + schunk * 8;
  const unsigned short* gA1p = gA0p + (size_t)128 * K_DIM;
  const unsigned short* gB0p = Bp + (size_t)(bn * 256 + wid * 8 + srow) * K_DIM + schunk * 8;
  const unsigned short* gB1p = gB0p + (size_t)128 * K_DIM;

  // LDS read bases (byte ptrs); frag row&7 == lane&7 for all fragment rows.
  int c15 = lane & 15;
  int kl = lane >> 4;                   // k-group 0..3
  const char* ldsAr = lds + wm * 16384 + c15 * 128;
  const char* ldsBr = lds + 65536 + (wn >> 1) * 16384 + ((wn & 1) * 64 + c15) * 128;
  int rd0 = ((kl) ^ (lane & 7)) << 4;         // kk=0 chunk
  int rd1 = ((4 | kl) ^ (lane & 7)) << 4;     // kk=1 chunk

  f32x4 acc[8][4];
  f32x4 zero = {0.f, 0.f, 0.f, 0.f};
#pragma unroll
  for (int m = 0; m < 8; ++m)
#pragma unroll
    for (int n = 0; n < 4; ++n) acc[m][n] = zero;

  bf16x8 AQa[4], AQb[4];   // A-quarter ping/pong (4 m-frags x 1 kk each)
  bf16x8 BHa[4], BHb[4];   // B kk-half ping/pong (4 n-frags each)

  // ---- prologue: stage tile0 -> buf0, tile1 -> buf1 (16 loads);
  // vmcnt(8) -> buf0 landed; pre-read p0 operands. ----
  STAGE(gA0p, 0, 0);
  STAGE(gA1p, 16384, 0);
  STAGE(gB0p, 65536, 0);
  STAGE(gB1p, 65536 + 16384, 0);
  STAGE(gA0p, 32768, 1);
  STAGE(gA1p, 32768 + 16384, 1);
  STAGE(gB0p, 65536 + 32768, 1);
  STAGE(gB1p, 65536 + 32768 + 16384, 1);
  asm volatile("s_waitcnt vmcnt(8)" ::: "memory");
  __builtin_amdgcn_s_barrier();
  RD_AQ(AQa, 0, rd0, 0);
  RD_BH(BHa, rd0, 0);

#pragma unroll 1
  for (int kt = 0; kt < NKT; kt += 2) {
    KTILE(0, kt);
    KTILE(1, kt + 1);
  }

  // ---- fused LSTM epilogue: lane owns hidden unit h; acc[mi][g][j] = gate g ----
  int h = (bn * 4 + wn) * 16 + c15;
  float bi = bxi[h] + bhi[h];
  float bf_ = bxf[h] + bhf[h];
  float bc = bxc[h] + bhc[h];
  float bo = bxo[h] + bho[h];
  int row0 = bm * 256 + wm * 128 + kl * 4;
#pragma unroll
  for (int mi = 0; mi < 8; ++mi) {
#pragma unroll
    for (int j = 0; j < 4; ++j) {
      int r = row0 + mi * 16 + j;
      size_t off = (size_t)r * H_DIM + h;
      float zi = acc[mi][0][j] + bi;
      float zf = acc[mi][1][j] + bf_;
      float zc = acc[mi][2][j] + bc;
      float zo = acc[mi][3][j] + bo;
      float ig = 1.f / (1.f + __expf(-zi));
      float fg = 1.f / (1.f + __expf(-zf));
      float e2 = __expf(-2.f * zc);
      float gg = (1.f - e2) / (1.f + e2);       // tanh(zc)
      float og = 1.f / (1.f + __expf(-zo));
      float cp = c_prev[off];
      float cn = fg * cp + ig * gg;
      float e2c = __expf(-2.f * cn);
      float th = (1.f - e2c) / (1.f + e2c);     // tanh(cn)
      out[off] = og * th;                        // h_new
      out[(size_t)B_DIM * H_DIM + off] = cn;     // c_new
    }
  }
}

extern "C" void kernel_launch(void* const* d_in, const int* in_sizes, int n_in,
                              void* d_out, int out_size, void* d_ws, size_t ws_size,
                              hipStream_t stream) {
  const float* x      = (const float*)d_in[0];
  const float* h_prev = (const float*)d_in[1];
  const float* c_prev = (const float*)d_in[2];
  const float* Wxi = (const float*)d_in[3];
  const float* Whi = (const float*)d_in[4];
  const float* Wxf = (const float*)d_in[5];
  const float* Whf = (const float*)d_in[6];
  const float* Wxc = (const float*)d_in[7];
  const float* Whc = (const float*)d_in[8];
  const float* Wxo = (const float*)d_in[9];
  const float* Who = (const float*)d_in[10];
  const float* bxi = (const float*)d_in[11];
  const float* bhi = (const float*)d_in[12];
  const float* bxf = (const float*)d_in[13];
  const float* bhf = (const float*)d_in[14];
  const float* bxc = (const float*)d_in[15];
  const float* bhc = (const float*)d_in[16];
  const float* bxo = (const float*)d_in[17];
  const float* bho = (const float*)d_in[18];

  unsigned short* Abf = (unsigned short*)d_ws;                                      // 32 MiB
  unsigned short* Bbf = (unsigned short*)((char*)d_ws + (size_t)B_DIM * K_DIM * 2); // +16 MiB

  pack_AB_kernel<<<2048, 256, 0, stream>>>(x, h_prev,
      Wxi, Whi, Wxf, Whf, Wxc, Whc, Wxo, Who, Abf, Bbf);
  lstm_gemm_kernel<<<512, 512, 0, stream>>>(Abf, Bbf, c_prev,
      bxi, bhi, bxf, bhf, bxc, bhc, bxo, bho, (float*)d_out);
}